// Round 18
// baseline (1263.973 us; speedup 1.0000x reference)
//
#include <hip/hip_runtime.h>

typedef unsigned short u16;
typedef float  f32x4  __attribute__((ext_vector_type(4)));
typedef short  bf16x8 __attribute__((ext_vector_type(8)));
typedef u16    u16x8  __attribute__((ext_vector_type(8)));

#define BROWS 32768
#define KTOT  3584
#define NKT   (KTOT / 64)     // 56 K-tiles
#define NIT   (NKT / 2)       // 28 two-tile iterations

static __device__ __forceinline__ u16 f2b(float f) {
    unsigned x = __float_as_uint(f);
    x += 0x7fffu + ((x >> 16) & 1u);        // round-to-nearest-even
    return (u16)(x >> 16);
}
static __device__ __forceinline__ float b2f(u16 u) {
    return __uint_as_float(((unsigned)u) << 16);
}
static __device__ __forceinline__ float sigm(float x) {
    return 1.f / (1.f + __expf(-x));
}
static __device__ __forceinline__ float tanh_s(float x) {
    float ax = fabsf(x);
    float e  = __expf(-2.f * ax);
    float t  = (1.f - e) / (1.f + e);
    return copysignf(t, x);
}
static __device__ __forceinline__ void gld16(const u16* g, u16* l) {
    __builtin_amdgcn_global_load_lds(
        (const __attribute__((address_space(1))) void*)g,
        (__attribute__((address_space(3))) void*)l, 16, 0, 0);
}

// ---------------------------------------------------------------------------
// pack_x: Xcat[b] = [bf16(emb[y[b]]) | bf16(s[b]) | bf16(c[b])]   (B x 3584)
// ---------------------------------------------------------------------------
__global__ __launch_bounds__(256) void pack_x(
    const float* __restrict__ s, const int* __restrict__ y,
    const float* __restrict__ c, const float* __restrict__ emb,
    u16* __restrict__ X)
{
    long tid = (long)blockIdx.x * 256 + threadIdx.x;   // B*448 threads
    int  row = (int)(tid / 448);
    int  seg = (int)(tid % 448);
    int  e0  = seg * 8;
    const float* src;
    if (e0 < 512)        src = emb + (long)y[row] * 512 + e0;
    else if (e0 < 1536)  src = s   + (long)row * 1024 + (e0 - 512);
    else                 src = c   + (long)row * 2048 + (e0 - 1536);
    f32x4 a = *(const f32x4*)src;
    f32x4 b = *(const f32x4*)(src + 4);
    u16x8 o;
    o[0]=f2b(a[0]); o[1]=f2b(a[1]); o[2]=f2b(a[2]); o[3]=f2b(a[3]);
    o[4]=f2b(b[0]); o[5]=f2b(b[1]); o[6]=f2b(b[2]); o[7]=f2b(b[3]);
    *(u16x8*)&X[(long)row * KTOT + e0] = o;
}

// ---------------------------------------------------------------------------
// wtrans_all: all 9 weight transposes in one launch.
// dst[n*KTOT + k] = bf16(src[k*1024 + n]).
// ---------------------------------------------------------------------------
__global__ __launch_bounds__(256) void wtrans_all(
    const float* __restrict__ Wz, const float* __restrict__ Uz,
    const float* __restrict__ Cz, const float* __restrict__ Wr,
    const float* __restrict__ Ur, const float* __restrict__ Cr,
    const float* __restrict__ W,  const float* __restrict__ U,
    const float* __restrict__ C,
    u16* __restrict__ WzrT, u16* __restrict__ W2T)
{
    __shared__ float t[32][33];
    int z = blockIdx.z;
    const float* src; u16* dst; int kd;
    switch (z) {
        case 0: src = Wz; dst = WzrT + 0;                  kd = 512;  break;
        case 1: src = Uz; dst = WzrT + 512;                kd = 1024; break;
        case 2: src = Cz; dst = WzrT + 1536;               kd = 2048; break;
        case 3: src = Wr; dst = WzrT + 1024 * KTOT;        kd = 512;  break;
        case 4: src = Ur; dst = WzrT + 1024 * KTOT + 512;  kd = 1024; break;
        case 5: src = Cr; dst = WzrT + 1024 * KTOT + 1536; kd = 2048; break;
        case 6: src = W;  dst = W2T + 0;                   kd = 512;  break;
        case 7: src = U;  dst = W2T + 512;                 kd = 1024; break;
        default: src = C; dst = W2T + 1536;                kd = 2048; break;
    }
    int k0 = blockIdx.x * 32;
    if (k0 >= kd) return;
    int n0 = blockIdx.y * 32;
    int tx = threadIdx.x, ty = threadIdx.y;
    #pragma unroll
    for (int r = ty; r < 32; r += 8)
        t[r][tx] = src[(long)(k0 + r) * 1024 + n0 + tx];
    __syncthreads();
    #pragma unroll
    for (int r = ty; r < 32; r += 8)
        dst[(long)(n0 + r) * KTOT + k0 + tx] = f2b(t[tx][r]);
}

// ---------------------------------------------------------------------------
// 256x256x64 8-wave GEMM, m201 fine interleave (T3+T4), LOW-PRESSURE operands:
//   a[8][2] held per K-tile (64 VGPR); bb CYCLED as [2][2] (16 VGPR):
//   P0 reads b0-1, P1 reads b2-3 (overwrite), P2 holds, P3 RE-READS b0-1.
//   This removes r15's 96-reg operand live-set (bb[0-1] lived P0->P3) that
//   caused the accumulator spill (WRITE 131->275 MB).
// Phases per 2-K-tile iteration (r15 skeleton, correctness-proven):
//   P0: rd a0-3,b0-1(cur) ; stage B0(next)   ; LGKM8 ; MFMA Q(m0-3,n0-1)
//   P1: rd a4-7,b2-3(cur) ; stage B1(next)   ; LGKM8 ; MFMA Q(m4-7,n2-3)
//   P2:                     stage A0(cur+2)  ;         MFMA Q(m0-3,n2-3)
//   P3: rd b0-1(cur)      ; stage A1(cur+2) + GATE vmcnt(4) ; MFMA Q(m4-7,n0-1)
// Gate audit (2 loads/half-tile, in-order retire): at P3, outstanding =
//   A(o)4 + B(o)4 + A(e+2)4 = 12; vmcnt(4) retires A(o),B(o) -> tile o cert.
// New-read safety: P3 reads even-B; even-B next written at P4 (after P3-MID
//   lgkm(0) + P3-END barrier). P7 reads odd-B; next written next-iter P0. OK.
// LDS per buffer (u16): A half0 [8192] | A half1 | B half0 | B half1
// st_16x32 swizzle via inverse-swizzled global source + swizzled ds_read.
// Epilogues read s as bf16 from Xcat cols [512,1536).
// ---------------------------------------------------------------------------

#define MF(av,bv,cv) __builtin_amdgcn_mfma_f32_16x16x32_bf16(av, bv, cv, 0, 0, 0)
#define RDA(P,m,ks)  a[m][ks] = *(const bf16x8*)((P) + (m)*1024 + (ks)*512 + lane_off)
#define RDA4(P,m0)   RDA(P,m0,0);RDA(P,m0,1);RDA(P,m0+1,0);RDA(P,m0+1,1);RDA(P,m0+2,0);RDA(P,m0+2,1);RDA(P,m0+3,0);RDA(P,m0+3,1)
#define RDB2n(P,n0) \
    bb[0][0] = *(const bf16x8*)((P) + (n0)*1024 +       lane_off); \
    bb[0][1] = *(const bf16x8*)((P) + (n0)*1024 + 512 + lane_off); \
    bb[1][0] = *(const bf16x8*)((P) + (n0+1)*1024 +       lane_off); \
    bb[1][1] = *(const bf16x8*)((P) + (n0+1)*1024 + 512 + lane_off);
#define MMR2(m,n0) \
    acc[m][n0]   = MF(a[m][0], bb[0][0], acc[m][n0]); \
    acc[m][n0]   = MF(a[m][1], bb[0][1], acc[m][n0]); \
    acc[m][n0+1] = MF(a[m][0], bb[1][0], acc[m][n0+1]); \
    acc[m][n0+1] = MF(a[m][1], bb[1][1], acc[m][n0+1]);
#define MMQUAD2(m0,n0) MMR2(m0,n0); MMR2(m0+1,n0); MMR2(m0+2,n0); MMR2(m0+3,n0)

#define LGKM8 asm volatile("s_waitcnt lgkmcnt(8)" ::: "memory");
#define PH_MID \
    __builtin_amdgcn_s_barrier(); \
    asm volatile("s_waitcnt lgkmcnt(0)" ::: "memory"); \
    __builtin_amdgcn_sched_barrier(0); \
    __builtin_amdgcn_s_setprio(1);
#define PH_END \
    __builtin_amdgcn_s_setprio(0); \
    __builtin_amdgcn_sched_barrier(0); \
    __builtin_amdgcn_s_barrier();

template<int MODE>
__global__ __launch_bounds__(512, 1) void gemm8(
    const u16* __restrict__ Xc, const u16* __restrict__ rsin,
    const u16* __restrict__ Wt,
    u16* __restrict__ zb, u16* __restrict__ rsb,
    const u16* __restrict__ zread, float* __restrict__ out, int NT)
{
    extern __shared__ u16 smem[];   // 2 x 32768 u16 = 128 KiB

    int bid = blockIdx.x, nwg = gridDim.x;
    int q   = nwg >> 3;                        // nwg divisible by 8
    int wg  = (bid & 7) * q + (bid >> 3);      // XCD-contiguous swizzle
    int bm  = wg / NT, bn = wg % NT;
    int R0  = bm * 256;
    int C0  = bn * 256;

    int t = threadIdx.x, w = t >> 6, l = t & 63;
    int wr = w >> 2, wc = w & 3;               // 2 x 4 wave grid

    // ---- staging constants (inverse-swizzled global source) ----
    int rl   = l >> 2;                               // subtile row 0..15
    int ccl  = ((l & 3) * 8) ^ ((l >> 5) * 16);      // subtile col (elements)
    int sr0  = w >> 1, sc = w & 1;
    int colb = sc * 32 + ccl;
    int offAx[2][2], offAr[2][2], offB[2][2];
    #pragma unroll
    for (int h = 0; h < 2; h++)
        #pragma unroll
        for (int i = 0; i < 2; i++) {
            int row = h * 128 + (sr0 + i * 4) * 16 + rl;
            offAx[h][i] = (R0 + row) * KTOT + colb;
            offAr[h][i] = (R0 + row) * 1024 + colb - 512;   // rs segment (MODE 1)
            offB [h][i] = (C0 + row) * KTOT + colb;
        }

    // stage ONE half-tile (2 gld16/thread). h = half index 0..1
    auto stageA = [&](int kt, int h) {
        int k0 = kt * 64;
        u16* Ld = smem + (kt & 1) * 32768 + h * 8192;
        bool useR = (MODE == 1) && (k0 >= 512) && (k0 < 1536);
        #pragma unroll
        for (int i = 0; i < 2; i++) {
            const u16* g = useR ? (rsin + (offAr[h][i] + k0))
                                : (Xc   + (offAx[h][i] + k0));
            gld16(g, Ld + (w + i * 8) * 512);
        }
    };
    auto stageB = [&](int kt, int h) {
        int k0 = kt * 64;
        u16* Ld = smem + (kt & 1) * 32768 + 16384 + h * 8192;
        #pragma unroll
        for (int i = 0; i < 2; i++)
            gld16(Wt + (offB[h][i] + k0), Ld + (w + i * 8) * 512);
    };

    // ---- read-side swizzled lane offset (u16 units) ----
    int lane_off = (l & 15) * 32 + (((l >> 4) * 8) ^ (((l >> 3) & 1) * 16));

    const u16* Ae = smem + wr * 8192;                                // buf0 A
    const u16* Be = smem + 16384 + (wc >> 1) * 8192 + (wc & 1) * 4096;
    const u16* Ao = Ae + 32768;                                      // buf1
    const u16* Bo = Be + 32768;

    f32x4 acc[8][4];
    #pragma unroll
    for (int m = 0; m < 8; m++)
        #pragma unroll
        for (int n = 0; n < 4; n++)
            acc[m][n] = (f32x4){0.f, 0.f, 0.f, 0.f};

    bf16x8 a[8][2];
    bf16x8 bb[2][2];

    // ---- prologue: T0 full + T1 A-halves; vmcnt(4) retires exactly T0 ----
    stageA(0, 0); stageA(0, 1); stageB(0, 0); stageB(0, 1);
    stageA(1, 0); stageA(1, 1);
    asm volatile("s_waitcnt vmcnt(4)" ::: "memory");
    __builtin_amdgcn_s_barrier();

    #pragma unroll 1
    for (int it = 0; it < NIT - 1; ++it) {
        int e = 2 * it, o = e + 1;
        // ======== even K-tile (buffer0) ========
        // P0: rd a0-3, b0-1 ; stage B0(o)
        RDA4(Ae, 0); RDB2n(Be, 0); stageB(o, 0);
        LGKM8; PH_MID; MMQUAD2(0, 0); PH_END;
        // P1: rd a4-7, b2-3 ; stage B1(o)
        RDA4(Ae, 4); RDB2n(Be, 2); stageB(o, 1);
        LGKM8; PH_MID; MMQUAD2(4, 2); PH_END;
        // P2: stage A0(e+2) ; MFMA (m0-3, n2-3) from held regs
        stageA(e + 2, 0);
        PH_MID; MMQUAD2(0, 2); PH_END;
        // P3: re-read b0-1 ; stage A1(e+2) ; GATE vmcnt(4) -> tile o certified
        RDB2n(Be, 0); stageA(e + 2, 1);
        asm volatile("s_waitcnt vmcnt(4)" ::: "memory");
        PH_MID; MMQUAD2(4, 0); PH_END;
        // ======== odd K-tile (buffer1) ========
        // P4: rd a0-3, b0-1 ; stage B0(e+2)
        RDA4(Ao, 0); RDB2n(Bo, 0); stageB(e + 2, 0);
        LGKM8; PH_MID; MMQUAD2(0, 0); PH_END;
        // P5: rd a4-7, b2-3 ; stage B1(e+2)
        RDA4(Ao, 4); RDB2n(Bo, 2); stageB(e + 2, 1);
        LGKM8; PH_MID; MMQUAD2(4, 2); PH_END;
        // P6: stage A0(o+2)
        stageA(o + 2, 0);
        PH_MID; MMQUAD2(0, 2); PH_END;
        // P7: re-read b0-1 ; stage A1(o+2) ; GATE vmcnt(4) -> tile e+2 cert.
        RDB2n(Bo, 0); stageA(o + 2, 1);
        asm volatile("s_waitcnt vmcnt(4)" ::: "memory");
        PH_MID; MMQUAD2(4, 0); PH_END;
    }

    // ---- tail iteration (tiles 54, 55): stage only B(55), drain gates ----
    {
        RDA4(Ae, 0); RDB2n(Be, 0); stageB(NKT - 1, 0);
        LGKM8; PH_MID; MMQUAD2(0, 0); PH_END;
        RDA4(Ae, 4); RDB2n(Be, 2); stageB(NKT - 1, 1);
        LGKM8; PH_MID; MMQUAD2(4, 2); PH_END;
        PH_MID; MMQUAD2(0, 2); PH_END;
        RDB2n(Be, 0);
        asm volatile("s_waitcnt vmcnt(0)" ::: "memory");
        PH_MID; MMQUAD2(4, 0); PH_END;
        RDA4(Ao, 0); RDB2n(Bo, 0);
        PH_MID; MMQUAD2(0, 0); PH_END;
        RDA4(Ao, 4); RDB2n(Bo, 2);
        PH_MID; MMQUAD2(4, 2); PH_END;
        PH_MID; MMQUAD2(0, 2); PH_END;
        RDB2n(Bo, 0);
        PH_MID; MMQUAD2(4, 0); PH_END;
    }

    // ---- epilogue: C/D layout col=lane&15, row=(lane>>4)*4+j ----
    // s (prev state) read as bf16 from Xcat cols [512,1536)
    int lr = (l >> 4) * 4, lc = l & 15;
    long R0w = R0 + wr * 128;
    int  C0w = C0 + wc * 64;
    if (MODE == 0) {
        if (C0 < 1024) {                       // whole tile in z region
            #pragma unroll
            for (int m = 0; m < 8; m++)
                #pragma unroll
                for (int n = 0; n < 4; n++) {
                    int col = C0w + n * 16 + lc;
                    #pragma unroll
                    for (int j = 0; j < 4; j++) {
                        long r = R0w + m * 16 + lr + j;
                        zb[r * 1024 + col] = f2b(sigm(acc[m][n][j]));
                    }
                }
        } else {                               // whole tile in r region
            #pragma unroll
            for (int m = 0; m < 8; m++)
                #pragma unroll
                for (int n = 0; n < 4; n++) {
                    int h = C0w + n * 16 + lc - 1024;
                    #pragma unroll
                    for (int j = 0; j < 4; j++) {
                        long r = R0w + m * 16 + lr + j;
                        float sv = b2f(Xc[r * KTOT + 512 + h]);
                        float rr = sigm(acc[m][n][j]);
                        rsb[r * 1024 + h] = f2b(rr * sv);
                    }
                }
        }
    } else {
        #pragma unroll
        for (int m = 0; m < 8; m++)
            #pragma unroll
            for (int n = 0; n < 4; n++) {
                int col = C0w + n * 16 + lc;
                #pragma unroll
                for (int j = 0; j < 4; j++) {
                    long r = R0w + m * 16 + lr + j;
                    float st = tanh_s(acc[m][n][j]);
                    float z  = b2f(zread[r * 1024 + col]);
                    float sv = b2f(Xc[r * KTOT + 512 + col]);
                    out[r * 1024 + col] = fmaf(z, st - sv, sv);
                }
            }
    }
}

// ---------------------------------------------------------------------------
extern "C" void kernel_launch(void* const* d_in, const int* in_sizes, int n_in,
                              void* d_out, int out_size, void* d_ws, size_t ws_size,
                              hipStream_t stream)
{
    const float* s   = (const float*)d_in[0];
    const int*   y   = (const int*)  d_in[1];
    const float* c   = (const float*)d_in[2];
    const float* emb = (const float*)d_in[3];
    const float* Wz  = (const float*)d_in[4];
    const float* Uz  = (const float*)d_in[5];
    const float* Cz  = (const float*)d_in[6];
    const float* Wr  = (const float*)d_in[7];
    const float* Ur  = (const float*)d_in[8];
    const float* Cr  = (const float*)d_in[9];
    const float* W   = (const float*)d_in[10];
    const float* U   = (const float*)d_in[11];
    const float* C   = (const float*)d_in[12];
    float* out = (float*)d_out;

    char* ws = (char*)d_ws;
    u16* Xcat = (u16*)(ws);                                  // B*3584*2
    u16* rsb  = (u16*)(ws + 234881024);                      // B*1024*2
    u16* zbuf = (u16*)(ws + 301989888);                      // B*1024*2
    u16* WzrT = (u16*)(ws + 369098752);                      // 2048*3584*2
    u16* W2T  = (u16*)(ws + 383778816);                      // 1024*3584*2

    hipFuncSetAttribute((const void*)gemm8<0>,
                        hipFuncAttributeMaxDynamicSharedMemorySize, 131072);
    hipFuncSetAttribute((const void*)gemm8<1>,
                        hipFuncAttributeMaxDynamicSharedMemorySize, 131072);

    pack_x<<<BROWS * 448 / 256, 256, 0, stream>>>(s, y, c, emb, Xcat);

    dim3 tb(32, 8);
    wtrans_all<<<dim3(64, 32, 9), tb, 0, stream>>>(
        Wz, Uz, Cz, Wr, Ur, Cr, W, U, C, WzrT, W2T);

    // GEMM1: (B x 3584) @ (3584 x 2048) -> z, rs   (128 x 8 = 1024 wgs)
    gemm8<0><<<(BROWS / 256) * (2048 / 256), 512, 131072, stream>>>(
        Xcat, nullptr, WzrT, zbuf, rsb, nullptr, nullptr, 2048 / 256);

    // GEMM2: ([y|rs|c] B x 3584) @ (3584 x 1024) -> out   (128 x 4 = 512 wgs)
    gemm8<1><<<(BROWS / 256) * (1024 / 256), 512, 131072, stream>>>(
        Xcat, rsb, W2T, nullptr, nullptr, zbuf, out, 1024 / 256);
}

// Round 19
// 803.603 us; speedup vs baseline: 1.5729x; 1.5729x over previous
//
#include <hip/hip_runtime.h>

typedef unsigned short u16;
typedef float  f32x4  __attribute__((ext_vector_type(4)));
typedef short  bf16x8 __attribute__((ext_vector_type(8)));
typedef u16    u16x8  __attribute__((ext_vector_type(8)));

#define BROWS 32768
#define KTOT  3584
#define NKT   (KTOT / 64)

static __device__ __forceinline__ u16 f2b(float f) {
    unsigned x = __float_as_uint(f);
    x += 0x7fffu + ((x >> 16) & 1u);        // round-to-nearest-even
    return (u16)(x >> 16);
}
static __device__ __forceinline__ float b2f(u16 u) {
    return __uint_as_float(((unsigned)u) << 16);
}
static __device__ __forceinline__ float sigm(float x) {
    return 1.f / (1.f + __expf(-x));
}
static __device__ __forceinline__ float tanh_s(float x) {
    float ax = fabsf(x);
    float e  = __expf(-2.f * ax);
    float t  = (1.f - e) / (1.f + e);
    return copysignf(t, x);
}
static __device__ __forceinline__ void gld16(const u16* g, u16* l) {
    __builtin_amdgcn_global_load_lds(
        (const __attribute__((address_space(1))) void*)g,
        (__attribute__((address_space(3))) void*)l, 16, 0, 0);
}

// ---------------------------------------------------------------------------
// pack_x: Xcat[b] = [bf16(emb[y[b]]) | bf16(s[b]) | bf16(c[b])]   (B x 3584)
// ---------------------------------------------------------------------------
__global__ __launch_bounds__(256) void pack_x(
    const float* __restrict__ s, const int* __restrict__ y,
    const float* __restrict__ c, const float* __restrict__ emb,
    u16* __restrict__ X)
{
    long tid = (long)blockIdx.x * 256 + threadIdx.x;   // B*448 threads
    int  row = (int)(tid / 448);
    int  seg = (int)(tid % 448);
    int  e0  = seg * 8;
    const float* src;
    if (e0 < 512)        src = emb + (long)y[row] * 512 + e0;
    else if (e0 < 1536)  src = s   + (long)row * 1024 + (e0 - 512);
    else                 src = c   + (long)row * 2048 + (e0 - 1536);
    f32x4 a = *(const f32x4*)src;
    f32x4 b = *(const f32x4*)(src + 4);
    u16x8 o;
    o[0]=f2b(a[0]); o[1]=f2b(a[1]); o[2]=f2b(a[2]); o[3]=f2b(a[3]);
    o[4]=f2b(b[0]); o[5]=f2b(b[1]); o[6]=f2b(b[2]); o[7]=f2b(b[3]);
    *(u16x8*)&X[(long)row * KTOT + e0] = o;
}

// ---------------------------------------------------------------------------
// wtrans_all: all 9 weight transposes in one launch.
// dst[n*KTOT + k] = bf16(src[k*1024 + n]).
// ---------------------------------------------------------------------------
__global__ __launch_bounds__(256) void wtrans_all(
    const float* __restrict__ Wz, const float* __restrict__ Uz,
    const float* __restrict__ Cz, const float* __restrict__ Wr,
    const float* __restrict__ Ur, const float* __restrict__ Cr,
    const float* __restrict__ W,  const float* __restrict__ U,
    const float* __restrict__ C,
    u16* __restrict__ WzrT, u16* __restrict__ W2T)
{
    __shared__ float t[32][33];
    int z = blockIdx.z;
    const float* src; u16* dst; int kd;
    switch (z) {
        case 0: src = Wz; dst = WzrT + 0;                  kd = 512;  break;
        case 1: src = Uz; dst = WzrT + 512;                kd = 1024; break;
        case 2: src = Cz; dst = WzrT + 1536;               kd = 2048; break;
        case 3: src = Wr; dst = WzrT + 1024 * KTOT;        kd = 512;  break;
        case 4: src = Ur; dst = WzrT + 1024 * KTOT + 512;  kd = 1024; break;
        case 5: src = Cr; dst = WzrT + 1024 * KTOT + 1536; kd = 2048; break;
        case 6: src = W;  dst = W2T + 0;                   kd = 512;  break;
        case 7: src = U;  dst = W2T + 512;                 kd = 1024; break;
        default: src = C; dst = W2T + 1536;                kd = 2048; break;
    }
    int k0 = blockIdx.x * 32;
    if (k0 >= kd) return;
    int n0 = blockIdx.y * 32;
    int tx = threadIdx.x, ty = threadIdx.y;
    #pragma unroll
    for (int r = ty; r < 32; r += 8)
        t[r][tx] = src[(long)(k0 + r) * 1024 + n0 + tx];
    __syncthreads();
    #pragma unroll
    for (int r = ty; r < 32; r += 8)
        dst[(long)(n0 + r) * KTOT + k0 + tx] = f2b(t[tx][r]);
}

// ---------------------------------------------------------------------------
// 256x256x64 8-wave 4-phase GEMM (round-7/14 schedule -- session best, FINAL).
// Quadrant-pipelined ds_reads: operand reads for phase i+1 issue inside
// phase i's MFMA region. Staging: B@P2-top, A@P3-top; vmcnt(8) gate at P3
// retires exactly tile kt+1 (16 outstanding = 8 kt+1 + 8 just-issued kt+2).
// LDS per buffer (u16): A half0 [8192] | A half1 | B half0 | B half1
// st_16x32 swizzle via inverse-swizzled global source + swizzled ds_read.
// Epilogues read s as bf16 from Xcat cols [512,1536).
// Ceiling (session-established): MfmaUtil ~48% across 4 structural variants;
// the ~2500cyc/K-tile barrier/waitcnt train binds at 1 wg/CU. Fine-interleave
// spills acc (r3/r15/r18); 2wg-occupancy spills or regresses (r13/r16).
// ---------------------------------------------------------------------------

#define RDA(P,m,ks)  a[m][ks]  = *(const bf16x8*)((P) + (m)*1024 + (ks)*512 + lane_off)
#define RDB(P,n,ks)  bb[n][ks] = *(const bf16x8*)((P) + (n)*1024 + (ks)*512 + lane_off)
#define RDA4(P,m0)   RDA(P,m0,0);RDA(P,m0,1);RDA(P,m0+1,0);RDA(P,m0+1,1);RDA(P,m0+2,0);RDA(P,m0+2,1);RDA(P,m0+3,0);RDA(P,m0+3,1)
#define RDB2(P,n0)   RDB(P,n0,0);RDB(P,n0,1);RDB(P,n0+1,0);RDB(P,n0+1,1)
#define MM1(m,n,ks) acc[m][n] = __builtin_amdgcn_mfma_f32_16x16x32_bf16(a[m][ks], bb[n][ks], acc[m][n], 0, 0, 0)
#define MMROW(m,n0) MM1(m,n0,0); MM1(m,n0,1); MM1(m,n0+1,0); MM1(m,n0+1,1)
#define MMQUAD(m0,n0) MMROW(m0,n0); MMROW(m0+1,n0); MMROW(m0+2,n0); MMROW(m0+3,n0)

#define PH_MID \
    __builtin_amdgcn_s_barrier(); \
    asm volatile("s_waitcnt lgkmcnt(0)" ::: "memory"); \
    __builtin_amdgcn_sched_barrier(0); \
    __builtin_amdgcn_s_setprio(1);

#define PH_END \
    __builtin_amdgcn_s_setprio(0); \
    __builtin_amdgcn_sched_barrier(0); \
    __builtin_amdgcn_s_barrier();

#define PIN __builtin_amdgcn_sched_barrier(0);

template<int MODE>
__global__ __launch_bounds__(512, 1) void gemm8(
    const u16* __restrict__ Xc, const u16* __restrict__ rsin,
    const u16* __restrict__ Wt,
    u16* __restrict__ zb, u16* __restrict__ rsb,
    const u16* __restrict__ zread, float* __restrict__ out, int NT)
{
    extern __shared__ u16 smem[];   // 2 x 32768 u16 = 128 KiB

    int bid = blockIdx.x, nwg = gridDim.x;
    int q   = nwg >> 3;                        // nwg divisible by 8
    int wg  = (bid & 7) * q + (bid >> 3);      // XCD-contiguous swizzle
    int bm  = wg / NT, bn = wg % NT;
    int R0  = bm * 256;
    int C0  = bn * 256;

    int t = threadIdx.x, w = t >> 6, l = t & 63;
    int wr = w >> 2, wc = w & 3;               // 2 x 4 wave grid

    // ---- staging constants (inverse-swizzled global source) ----
    int rl   = l >> 2;                               // subtile row 0..15
    int ccl  = ((l & 3) * 8) ^ ((l >> 5) * 16);      // subtile col (elements)
    int sr0  = w >> 1, sc = w & 1;
    int colb = sc * 32 + ccl;
    int offAx[2][2], offAr[2][2], offB[2][2];
    #pragma unroll
    for (int h = 0; h < 2; h++)
        #pragma unroll
        for (int i = 0; i < 2; i++) {
            int row = h * 128 + (sr0 + i * 4) * 16 + rl;
            offAx[h][i] = (R0 + row) * KTOT + colb;
            offAr[h][i] = (R0 + row) * 1024 + colb - 512;   // rs segment (MODE 1)
            offB [h][i] = (C0 + row) * KTOT + colb;
        }

    auto stageA = [&](int kt) {
        int k0 = kt * 64;
        u16* Ld = smem + (kt & 1) * 32768;
        bool useR = (MODE == 1) && (k0 >= 512) && (k0 < 1536);
        #pragma unroll
        for (int h = 0; h < 2; h++)
            #pragma unroll
            for (int i = 0; i < 2; i++) {
                const u16* g = useR ? (rsin + (offAr[h][i] + k0))
                                    : (Xc   + (offAx[h][i] + k0));
                gld16(g, Ld + h * 8192 + (w + i * 8) * 512);
            }
    };
    auto stageB = [&](int kt) {
        int k0 = kt * 64;
        u16* Ld = smem + (kt & 1) * 32768 + 16384;
        #pragma unroll
        for (int h = 0; h < 2; h++)
            #pragma unroll
            for (int i = 0; i < 2; i++)
                gld16(Wt + (offB[h][i] + k0),
                      Ld + h * 8192 + (w + i * 8) * 512);
    };

    // ---- read-side swizzled lane offset (u16 units) ----
    int lane_off = (l & 15) * 32 + (((l >> 4) * 8) ^ (((l >> 3) & 1) * 16));

    f32x4 acc[8][4];
    #pragma unroll
    for (int m = 0; m < 8; m++)
        #pragma unroll
        for (int n = 0; n < 4; n++)
            acc[m][n] = (f32x4){0.f, 0.f, 0.f, 0.f};

    bf16x8 a[8][2], bb[4][2];

    int aoff = wr * 8192;
    int boff = 16384 + (wc >> 1) * 8192 + (wc & 1) * 4096;

    // ---- prologue: stage tiles 0 and 1; certify T0; preload Q0 regs ----
    stageA(0); stageB(0);
    stageA(1); stageB(1);
    asm volatile("s_waitcnt vmcnt(8)" ::: "memory");   // tile 0 landed
    __builtin_amdgcn_s_barrier();
    {
        const u16* A0 = smem + aoff;
        const u16* B0 = smem + boff;
        RDA4(A0, 0); RDB2(B0, 0);
    }

    for (int kt = 0; kt < NKT; ++kt) {
        int bs = kt & 1;
        const u16* Ab = smem + bs * 32768 + aoff;
        const u16* Bb = smem + bs * 32768 + boff;
        const u16* An = smem + (bs ^ 1) * 32768 + aoff;
        const u16* Bn = smem + (bs ^ 1) * 32768 + boff;

        // P0: reads-first b2-3 (dead since prev-P2); then MFMA Q0
        PH_MID; RDB2(Bb, 2); PIN; MMQUAD(0, 0); PH_END;
        // P1: reads-first a4-7 (dead since prev-P3); then MFMA Q1
        PH_MID; RDA4(Ab, 4); PIN; MMQUAD(0, 2); PH_END;
        // P2: stage B(kt+2) (region free since P1-END); MFMA Q2
        if (kt + 2 < NKT) stageB(kt + 2);
        PH_MID; MMQUAD(4, 2); PH_END;
        // P3: stage A(kt+2); gate vmcnt(8) retires exactly tile kt+1;
        //     reads-first next a0-3 (dead since P1, certified by gate+barrier);
        //     MFMA Q3 (uses b0-1) ; next b0-1 read AFTER the MFMA
        if (kt + 2 < NKT) {
            stageA(kt + 2);
            asm volatile("s_waitcnt vmcnt(8)" ::: "memory");
        } else {
            asm volatile("s_waitcnt vmcnt(0)" ::: "memory");
        }
        PH_MID;
        if (kt + 1 < NKT) { RDA4(An, 0); }
        PIN;
        MMQUAD(4, 0);
        if (kt + 1 < NKT) { RDB2(Bn, 0); }
        PH_END;
    }

    // ---- epilogue: C/D layout col=lane&15, row=(lane>>4)*4+j ----
    // s (prev state) read as bf16 from Xcat cols [512,1536)
    int lr = (l >> 4) * 4, lc = l & 15;
    long R0w = R0 + wr * 128;
    int  C0w = C0 + wc * 64;
    if (MODE == 0) {
        if (C0 < 1024) {                       // whole tile in z region
            #pragma unroll
            for (int m = 0; m < 8; m++)
                #pragma unroll
                for (int n = 0; n < 4; n++) {
                    int col = C0w + n * 16 + lc;
                    #pragma unroll
                    for (int j = 0; j < 4; j++) {
                        long r = R0w + m * 16 + lr + j;
                        zb[r * 1024 + col] = f2b(sigm(acc[m][n][j]));
                    }
                }
        } else {                               // whole tile in r region
            #pragma unroll
            for (int m = 0; m < 8; m++)
                #pragma unroll
                for (int n = 0; n < 4; n++) {
                    int h = C0w + n * 16 + lc - 1024;
                    #pragma unroll
                    for (int j = 0; j < 4; j++) {
                        long r = R0w + m * 16 + lr + j;
                        float sv = b2f(Xc[r * KTOT + 512 + h]);
                        float rr = sigm(acc[m][n][j]);
                        rsb[r * 1024 + h] = f2b(rr * sv);
                    }
                }
        }
    } else {
        #pragma unroll
        for (int m = 0; m < 8; m++)
            #pragma unroll
            for (int n = 0; n < 4; n++) {
                int col = C0w + n * 16 + lc;
                #pragma unroll
                for (int j = 0; j < 4; j++) {
                    long r = R0w + m * 16 + lr + j;
                    float st = tanh_s(acc[m][n][j]);
                    float z  = b2f(zread[r * 1024 + col]);
                    float sv = b2f(Xc[r * KTOT + 512 + col]);
                    out[r * 1024 + col] = fmaf(z, st - sv, sv);
                }
            }
    }
}

// ---------------------------------------------------------------------------
extern "C" void kernel_launch(void* const* d_in, const int* in_sizes, int n_in,
                              void* d_out, int out_size, void* d_ws, size_t ws_size,
                              hipStream_t stream)
{
    const float* s   = (const float*)d_in[0];
    const int*   y   = (const int*)  d_in[1];
    const float* c   = (const float*)d_in[2];
    const float* emb = (const float*)d_in[3];
    const float* Wz  = (const float*)d_in[4];
    const float* Uz  = (const float*)d_in[5];
    const float* Cz  = (const float*)d_in[6];
    const float* Wr  = (const float*)d_in[7];
    const float* Ur  = (const float*)d_in[8];
    const float* Cr  = (const float*)d_in[9];
    const float* W   = (const float*)d_in[10];
    const float* U   = (const float*)d_in[11];
    const float* C   = (const float*)d_in[12];
    float* out = (float*)d_out;

    char* ws = (char*)d_ws;
    u16* Xcat = (u16*)(ws);                                  // B*3584*2
    u16* rsb  = (u16*)(ws + 234881024);                      // B*1024*2
    u16* zbuf = (u16*)(ws + 301989888);                      // B*1024*2
    u16* WzrT = (u16*)(ws + 369098752);                      // 2048*3584*2
    u16* W2T  = (u16*)(ws + 383778816);                      // 1024*3584*2

    hipFuncSetAttribute((const void*)gemm8<0>,
                        hipFuncAttributeMaxDynamicSharedMemorySize, 131072);
    hipFuncSetAttribute((const void*)gemm8<1>,
                        hipFuncAttributeMaxDynamicSharedMemorySize, 131072);

    pack_x<<<BROWS * 448 / 256, 256, 0, stream>>>(s, y, c, emb, Xcat);

    dim3 tb(32, 8);
    wtrans_all<<<dim3(64, 32, 9), tb, 0, stream>>>(
        Wz, Uz, Cz, Wr, Ur, Cr, W, U, C, WzrT, W2T);

    // GEMM1: (B x 3584) @ (3584 x 2048) -> z, rs   (128 x 8 = 1024 wgs)
    gemm8<0><<<(BROWS / 256) * (2048 / 256), 512, 131072, stream>>>(
        Xcat, nullptr, WzrT, zbuf, rsb, nullptr, nullptr, 2048 / 256);

    // GEMM2: ([y|rs|c] B x 3584) @ (3584 x 1024) -> out   (128 x 4 = 512 wgs)
    gemm8<1><<<(BROWS / 256) * (1024 / 256), 512, 131072, stream>>>(
        Xcat, rsb, W2T, nullptr, nullptr, zbuf, out, 1024 / 256);
}